// Round 5
// baseline (534.635 us; speedup 1.0000x reference)
//
#include <hip/hip_runtime.h>
#include <cstdint>
#include <cstddef>

#define KIN 300
#define KPAD 320
#define HIDDEN 128
#define BSZ 256
#define TSZ 512

// Phase-1 LDS row stride (shorts). 332*2/4 = 166 ≡ 6 (mod 32): bank spread.
#define ASTR 332
// Phase-1 epilogue stage: per-t_loc block = 16 u-groups x 136 shorts.
#define ST1 2176

typedef __attribute__((ext_vector_type(8))) short short8;
typedef __attribute__((ext_vector_type(4))) short s16x4;
typedef __attribute__((ext_vector_type(4))) float f32x4;

__device__ __forceinline__ short f2bf(float f) {
  uint32_t u = __builtin_bit_cast(uint32_t, f);
  u = (u + 0x7FFFu + ((u >> 16) & 1u)) >> 16;
  return (short)u;
}
__device__ __forceinline__ float bf2f(short s) {
  uint32_t u = ((uint32_t)(uint16_t)s) << 16;
  return __builtin_bit_cast(float, u);
}
__device__ __forceinline__ float bflo(uint32_t u) {
  return __builtin_bit_cast(float, u << 16);
}
__device__ __forceinline__ float bfhi(uint32_t u) {
  return __builtin_bit_cast(float, u & 0xFFFF0000u);
}
// HW packed f32->bf16 RNE convert: lo = bf16(a), hi = bf16(b). 1 inst vs ~10.
__device__ __forceinline__ uint32_t pack2bf(float a, float b) {
  uint32_t r;
  asm("v_cvt_pk_bf16_f32 %0, %1, %2" : "=v"(r) : "v"(a), "v"(b));
  return r;
}
// tanh(x) = 1 - 2/(exp2(x*2*log2e)+1); exact at +/-1 extremes, 5 VALU inst.
__device__ __forceinline__ float tanhf_fast(float v) {
  const float e = __builtin_amdgcn_exp2f(v * 2.88539008177793f);
  return fmaf(-2.0f, __builtin_amdgcn_rcpf(e + 1.0f), 1.0f);
}
// Barrier that waits LDS ops but leaves global/DMA (vmcnt) in flight.
__device__ __forceinline__ void barrier_lds() {
  asm volatile("s_waitcnt lgkmcnt(0)\n\ts_barrier" ::: "memory");
}
__device__ __forceinline__ void barrier_all() {
  asm volatile("s_waitcnt vmcnt(0) lgkmcnt(0)\n\ts_barrier" ::: "memory");
}
// async 16B/lane global->LDS DMA: lds dst = uniform base + lane*16
__device__ __forceinline__ void dma16(const short* g, short* l) {
  __builtin_amdgcn_global_load_lds(
      (const __attribute__((address_space(1))) void*)g,
      (__attribute__((address_space(3))) void*)l, 16, 0, 0);
}

// ---------------- Phase 0: W_ih -> bf16, K zero-padded to 320 --------------
__global__ __launch_bounds__(256) void wcvt_bf16(const float* __restrict__ W,
                                                 short* __restrict__ W16) {
  const int i = blockIdx.x * 256 + threadIdx.x;
  if (i >= HIDDEN * KPAD) return;
  const int n = i / KPAD, k = i % KPAD;
  W16[i] = (k < KIN) ? f2bf(W[n * KIN + k]) : (short)0;
}

// ---------------- Phase 1: xp = x @ W_ih^T + bias, DMA-native layout -------
// UNCHANGED (verified r4): emits [t][grp][u][b][8] with u = 4*(h>>5)+((h/4)&3),
// inner shorts [mt*4+r] -> one b128 per lane per step in the scan.
__global__ __launch_bounds__(256) void xp_gemm_mfma(
    const float* __restrict__ x, const short* __restrict__ W16,
    const float* __restrict__ b_ih, const float* __restrict__ b_hh,
    short* __restrict__ xp16) {
  __shared__ __align__(16) short As[64 * ASTR];  // 43 KB; reused as epilogue stage
  const int tid = threadIdx.x;
  const int lane = tid & 63, w = tid >> 6;
  const int q = lane >> 4, c = lane & 15;
  const int bg = blockIdx.x & 15, tc = blockIdx.x >> 4;
  const int b0 = bg * 16, t0 = tc * 4;

  // ---- stage x tile (64 rows x 300 K) as bf16, padded stride ASTR ----
#pragma unroll
  for (int i = 0; i < 19; ++i) {
    const int f = tid + 256 * i;  // float4 index over 64*75
    if (f < 4800) {
      const int rr = f / 75;
      const int k4 = f - rr * 75;
      const int b_in = rr >> 2, t_loc = rr & 3;
      const float4 v = *(const float4*)(
          x + ((size_t)(b0 + b_in) * TSZ + t0 + t_loc) * KIN + k4 * 4);
      uint2 pv;
      pv.x = pack2bf(v.x, v.y);
      pv.y = pack2bf(v.z, v.w);
      *(uint2*)&As[rr * ASTR + k4 * 4] = pv;
    }
  }
  if (tid < 64) {  // zero-pad k = 300..319
    const uint2 z = {0u, 0u};
#pragma unroll
    for (int j = 0; j < 5; ++j) *(uint2*)&As[tid * ASTR + 300 + j * 4] = z;
  }
  __syncthreads();

  // wave w owns h-tiles {2w, 2w+1} x all 4 row-tiles
  f32x4 acc[2][4];
#pragma unroll
  for (int ht = 0; ht < 2; ++ht)
#pragma unroll
    for (int rt = 0; rt < 4; ++rt) acc[ht][rt] = (f32x4){0.f, 0.f, 0.f, 0.f};

  // A-frags (W16, L2-resident): lane (q,c) -> A[m=c][k=q*8+j]
  const short* wp0 = W16 + (size_t)((2 * w + 0) * 16 + c) * KPAD + q * 8;
  const short* wp1 = W16 + (size_t)((2 * w + 1) * 16 + c) * KPAD + q * 8;
  // B-frag LDS base for this lane
  const short* bqp = &As[c * ASTR + q * 8];
  short8 af[2][2];
  short8 bq[2][4];
  af[0][0] = *(const short8*)(wp0);
  af[0][1] = *(const short8*)(wp1);
#pragma unroll
  for (int rt = 0; rt < 4; ++rt)
    bq[0][rt] = *(const short8*)(bqp + rt * 16 * ASTR);
#pragma unroll
  for (int kc = 0; kc < 10; ++kc) {
    const int cur = kc & 1;
    if (kc < 9) {
      af[cur ^ 1][0] = *(const short8*)(wp0 + (kc + 1) * 32);
      af[cur ^ 1][1] = *(const short8*)(wp1 + (kc + 1) * 32);
#pragma unroll
      for (int rt = 0; rt < 4; ++rt)
        bq[cur ^ 1][rt] = *(const short8*)(bqp + rt * 16 * ASTR + (kc + 1) * 32);
    }
#pragma unroll
    for (int ht = 0; ht < 2; ++ht)
#pragma unroll
      for (int rt = 0; rt < 4; ++rt)
        acc[ht][rt] = __builtin_amdgcn_mfma_f32_16x16x32_bf16(
            af[cur][ht], bq[cur][rt], acc[ht][rt], 0, 0, 0);
  }
  __syncthreads();  // all B-frag reads done; As becomes the stage buffer

  // ---- epilogue: bias, pack, LDS transpose to [t][u][b][8] (padded) ----
  float4 bsum[2];
#pragma unroll
  for (int ht = 0; ht < 2; ++ht) {
    const int h0 = (2 * w + ht) * 16 + q * 4;
    const float4 bi = *(const float4*)(b_ih + h0);
    const float4 bh = *(const float4*)(b_hh + h0);
    bsum[ht] = make_float4(bi.x + bh.x, bi.y + bh.y, bi.z + bh.z, bi.w + bh.w);
  }
  // stage layout: t stride ST1, u stride 136, b stride 8, mt offset 4
#pragma unroll
  for (int ht = 0; ht < 2; ++ht) {
    const int g = (2 * w + ht) * 4 + q;          // h-group = h/4, g in [0,32)
    const int u = 4 * (g >> 3) + (g & 3);        // scan u-index
    const int mt = (g >> 2) & 1;                 // scan m-tile parity
#pragma unroll
    for (int rt = 0; rt < 4; ++rt) {
      const int b_in = rt * 4 + (c >> 2);
      const int t_loc = c & 3;
      uint2 pv;
      pv.x = pack2bf(acc[ht][rt][0] + bsum[ht].x, acc[ht][rt][1] + bsum[ht].y);
      pv.y = pack2bf(acc[ht][rt][2] + bsum[ht].z, acc[ht][rt][3] + bsum[ht].w);
      *(uint2*)&As[t_loc * ST1 + u * 136 + b_in * 8 + mt * 4] = pv;
    }
  }
  __syncthreads();
  // ---- coalesced copy-out: per t_loc a dense 4 KB region ----
#pragma unroll
  for (int i = 0; i < 4; ++i) {
    const int4 vv =
        *(const int4*)&As[i * ST1 + (tid >> 4) * 136 + (tid & 15) * 8];
    *(int4*)(xp16 + ((size_t)(t0 + i) * 16 + bg) * 2048 + tid * 8) = vv;
  }
}

// ---------------- Phase 2: dual-recurrence MFMA scan + fused FC ------------
// 8 blocks x 512 threads. Waves 0-3 run recurrence A (batches bg*32..+16),
// waves 4-7 run B (+16..+32). Wave i sits on SIMD i%4 -> every SIMD holds one
// A-wave + one B-wave with INDEPENDENT chains: A's ds_read/MFMA/tanh latency
// hides under B's issue and vice versa, at the 4-wave-per-recurrence minimum
// broadcast cost (4 b128/wave/step).
// ht layout: [rec][par][c][k] k-linear stride 128 shorts, XOR granule swizzle
// (16B granule index ^= c&7): b128 reads land exactly 8 dwords per bank
// (the b128 floor), uint2 writes exactly 4/bank -> conflict-free by
// construction. Chunks = 4 steps (xs 64 KB + ht 16 KB = 80 KB LDS).
__global__ __launch_bounds__(512, 1) void rnn_scan_dma(
    const short* __restrict__ xp16, const float* __restrict__ Whh,
    const float* __restrict__ fc_w, const float* __restrict__ fc_b,
    float* __restrict__ out) {
  __shared__ __align__(16) short xs[2][4][2][2048];  // 64 KB [buf][s][rec][.]
  __shared__ __align__(16) short hts[8192];          // 16 KB [rec][par][c][128] swz
  const int tid = threadIdx.x;
  const int lane = tid & 63, w = tid >> 6;  // w = 0..7
  const int q = lane >> 4, c = lane & 15;
  const int rec = w >> 2, rw = w & 3;       // recurrence, wave-in-recurrence
  const int bg = blockIdx.x;                // 0..7
  const int c7 = c & 7;

  // W_hh A-frags: wave (rec,rw) owns rows [32rw, 32rw+32) as mt in {0,1}.
  short8 aw[2][4];
#pragma unroll
  for (int mt = 0; mt < 2; ++mt)
#pragma unroll
    for (int kc = 0; kc < 4; ++kc) {
      const float* src =
          Whh + (size_t)(32 * rw + 16 * mt + c) * HIDDEN + kc * 32 + q * 8;
      const float4 v0 = *(const float4*)(src);
      const float4 v1 = *(const float4*)(src + 4);
      short8 t;
      t[0] = f2bf(v0.x); t[1] = f2bf(v0.y); t[2] = f2bf(v0.z); t[3] = f2bf(v0.w);
      t[4] = f2bf(v1.x); t[5] = f2bf(v1.y); t[6] = f2bf(v1.z); t[7] = f2bf(v1.w);
      aw[mt][kc] = t;
    }

  // h0 = 0 (swizzle-invariant)
  for (int i = tid; i < 4096; i += 512) ((uint32_t*)hts)[i] = 0;

  // DMA issue: wave (rec, s=rw) covers one (step, rec) row = 4 x 1KB insts
#define ISSUE_CHUNK(CH, BUF)                                                  \
  {                                                                           \
    const short* srcb =                                                       \
        xp16 + ((size_t)((CH)*4 + rw) * 16 + (2 * bg + rec)) * 2048 +         \
        lane * 8;                                                             \
    _Pragma("unroll") for (int j = 0; j < 4; ++j)                             \
        dma16(srcb + j * 512, &xs[BUF][rw][rec][j * 512]);                    \
  }

  ISSUE_CHUNK(0, 0)
  barrier_all();  // chunk-0 DMA landed; ht zero + everyone ready

  // Read pointers: frag kc at k=32kc+8q -> granule (4kc+q)^c7, both parities.
  const int rbase0 = ((rec * 2 + 0) * 16 + c) * 128;
  const int rbase1 = rbase0 + 16 * 128;
  const short* rp0[4];
  const short* rp1[4];
#pragma unroll
  for (int kc = 0; kc < 4; ++kc) {
    const int off = ((4 * kc + q) ^ c7) * 8;
    rp0[kc] = hts + rbase0 + off;
    rp1[kc] = hts + rbase1 + off;
  }
  // Write offsets: mt0 at k=32rw+4q -> granule (4rw+(q>>1))^c7; mt1 +2.
  const int wo0 = ((4 * rw + (q >> 1)) ^ c7) * 8 + 4 * (q & 1);
  const int wo1 = ((4 * rw + 2 + (q >> 1)) ^ c7) * 8 + 4 * (q & 1);
  short* const wb0 = hts + rbase0;  // parity-0 write base (same c = batch)
  short* const wb1 = hts + rbase1;

  const int xsoff = (4 * rw + q) * 128 + c * 8;  // one b128 per step per lane

  for (int cc = 0; cc < 128; ++cc) {
    const int buf = cc & 1;
    if (cc + 1 < 128) ISSUE_CHUNK(cc + 1, buf ^ 1)
    // preload the whole chunk's xp for this lane (h-independent, dbuf'd)
    uint4 us[4];
#pragma unroll
    for (int s = 0; s < 4; ++s) us[s] = *(const uint4*)&xs[buf][s][rec][xsoff];
#pragma unroll
    for (int s = 0; s < 4; ++s) {
      const int rb = s & 1;  // global t = cc*4+s; 4|steps so parity = s&1
      const short8 bh0 = *(const short8*)(rb ? rp1[0] : rp0[0]);
      const short8 bh1 = *(const short8*)(rb ? rp1[1] : rp0[1]);
      const short8 bh2 = *(const short8*)(rb ? rp1[2] : rp0[2]);
      const short8 bh3 = *(const short8*)(rb ? rp1[3] : rp0[3]);
      f32x4 p0 = {bflo(us[s].x), bfhi(us[s].x), bflo(us[s].y), bfhi(us[s].y)};
      f32x4 p1 = {bflo(us[s].z), bfhi(us[s].z), bflo(us[s].w), bfhi(us[s].w)};
      f32x4 r0 = {0.f, 0.f, 0.f, 0.f};
      f32x4 r1 = {0.f, 0.f, 0.f, 0.f};
      p0 = __builtin_amdgcn_mfma_f32_16x16x32_bf16(aw[0][0], bh0, p0, 0, 0, 0);
      r0 = __builtin_amdgcn_mfma_f32_16x16x32_bf16(aw[0][2], bh2, r0, 0, 0, 0);
      p1 = __builtin_amdgcn_mfma_f32_16x16x32_bf16(aw[1][0], bh0, p1, 0, 0, 0);
      r1 = __builtin_amdgcn_mfma_f32_16x16x32_bf16(aw[1][2], bh2, r1, 0, 0, 0);
      p0 = __builtin_amdgcn_mfma_f32_16x16x32_bf16(aw[0][1], bh1, p0, 0, 0, 0);
      r0 = __builtin_amdgcn_mfma_f32_16x16x32_bf16(aw[0][3], bh3, r0, 0, 0, 0);
      p1 = __builtin_amdgcn_mfma_f32_16x16x32_bf16(aw[1][1], bh1, p1, 0, 0, 0);
      r1 = __builtin_amdgcn_mfma_f32_16x16x32_bf16(aw[1][3], bh3, r1, 0, 0, 0);
      const f32x4 s0 = p0 + r0;
      const f32x4 s1 = p1 + r1;
      uint2 w0, w1;
      w0.x = pack2bf(tanhf_fast(s0[0]), tanhf_fast(s0[1]));
      w0.y = pack2bf(tanhf_fast(s0[2]), tanhf_fast(s0[3]));
      w1.x = pack2bf(tanhf_fast(s1[0]), tanhf_fast(s1[1]));
      w1.y = pack2bf(tanhf_fast(s1[2]), tanhf_fast(s1[3]));
      short* const wb = rb ? wb0 : wb1;  // write parity rb^1
      *(uint2*)(wb + wo0) = w0;          // mt0 rows
      *(uint2*)(wb + wo1) = w1;          // mt1 rows
      barrier_lds();
    }
    barrier_all();  // next chunk's DMA (issued ~4 steps ago) must be landed
  }
#undef ISSUE_CHUNK

  // h_last in parity 0 (t=511 wrote rb^1 = 0), swizzled. FC: 64 outs/block.
  if (tid < 64) {
    const int bi2 = tid >> 1;                 // 0..31
    const int r_ = bi2 >> 4, bi = bi2 & 15, cls = tid & 1;
    float sacc = fc_b[cls];
    const float* fw = fc_w + cls * HIDDEN;
    const short* hb = hts + ((r_ * 2 + 0) * 16 + bi) * 128;
    const int b7 = bi & 7;
#pragma unroll 4
    for (int g = 0; g < 16; ++g) {            // granule = k>>3
      const short* gp = hb + (g ^ b7) * 8;
#pragma unroll
      for (int j = 0; j < 8; ++j)
        sacc = fmaf(bf2f(gp[j]), fw[g * 8 + j], sacc);
    }
    out[(bg * 32 + r_ * 16 + bi) * 2 + cls] = sacc;
  }
}

extern "C" void kernel_launch(void* const* d_in, const int* in_sizes, int n_in,
                              void* d_out, int out_size, void* d_ws, size_t ws_size,
                              hipStream_t stream) {
  const float* x    = (const float*)d_in[0];
  const float* W_ih = (const float*)d_in[1];
  const float* W_hh = (const float*)d_in[2];
  const float* b_ih = (const float*)d_in[3];
  const float* b_hh = (const float*)d_in[4];
  const float* fc_w = (const float*)d_in[5];
  const float* fc_b = (const float*)d_in[6];
  short* xp16 = (short*)d_ws;                         // 32 MiB bf16 [T][16grp][2048]
  short* W16  = (short*)((char*)d_ws + (33u << 20));  // 80 KB bf16 [128][320]
  float* out  = (float*)d_out;

  wcvt_bf16<<<(HIDDEN * KPAD + 255) / 256, 256, 0, stream>>>(W_ih, W16);
  xp_gemm_mfma<<<16 * (TSZ / 4), 256, 0, stream>>>(x, W16, b_ih, b_hh, xp16);
  rnn_scan_dma<<<8, 512, 0, stream>>>(xp16, W_hh, fc_w, fc_b, out);
}

// Round 6
// 452.773 us; speedup vs baseline: 1.1808x; 1.1808x over previous
//
#include <hip/hip_runtime.h>
#include <cstdint>
#include <cstddef>

#define KIN 300
#define KPAD 320
#define HIDDEN 128
#define BSZ 256
#define TSZ 512

// Phase-1 LDS row stride (shorts). 332*2/4 = 166 ≡ 6 (mod 32): bank spread.
#define ASTR 332

typedef __attribute__((ext_vector_type(8))) short short8;
typedef __attribute__((ext_vector_type(4))) short s16x4;
typedef __attribute__((ext_vector_type(4))) float f32x4;

__device__ __forceinline__ short f2bf(float f) {
  uint32_t u = __builtin_bit_cast(uint32_t, f);
  u = (u + 0x7FFFu + ((u >> 16) & 1u)) >> 16;
  return (short)u;
}
__device__ __forceinline__ float bf2f(short s) {
  uint32_t u = ((uint32_t)(uint16_t)s) << 16;
  return __builtin_bit_cast(float, u);
}
__device__ __forceinline__ float bflo(uint32_t u) {
  return __builtin_bit_cast(float, u << 16);
}
__device__ __forceinline__ float bfhi(uint32_t u) {
  return __builtin_bit_cast(float, u & 0xFFFF0000u);
}
// HW packed f32->bf16 RNE convert: lo = bf16(a), hi = bf16(b). 1 inst vs ~10.
__device__ __forceinline__ uint32_t pack2bf(float a, float b) {
  uint32_t r;
  asm("v_cvt_pk_bf16_f32 %0, %1, %2" : "=v"(r) : "v"(a), "v"(b));
  return r;
}
// tanh(x) = 1 - 2/(exp2(x*2*log2e)+1); exact at +/-1 extremes, 5 VALU inst.
__device__ __forceinline__ float tanhf_fast(float v) {
  const float e = __builtin_amdgcn_exp2f(v * 2.88539008177793f);
  return fmaf(-2.0f, __builtin_amdgcn_rcpf(e + 1.0f), 1.0f);
}
// Barrier that waits LDS ops but leaves global/DMA (vmcnt) in flight.
__device__ __forceinline__ void barrier_lds() {
  asm volatile("s_waitcnt lgkmcnt(0)\n\ts_barrier" ::: "memory");
}
__device__ __forceinline__ void barrier_all() {
  asm volatile("s_waitcnt vmcnt(0) lgkmcnt(0)\n\ts_barrier" ::: "memory");
}
// async 16B/lane global->LDS DMA: lds dst = uniform base + lane*16
__device__ __forceinline__ void dma16(const short* g, short* l) {
  __builtin_amdgcn_global_load_lds(
      (const __attribute__((address_space(1))) void*)g,
      (__attribute__((address_space(3))) void*)l, 16, 0, 0);
}
// Load a bf16 MFMA fragment from the split ht layout: 8 values as two
// separated short4 groups (can't be merged into a conflicting b128).
__device__ __forceinline__ short8 ld_bh(const short* lo) {
  const s16x4 a = *(const s16x4*)lo;
  const s16x4 b = *(const s16x4*)(lo + 64);
  return __builtin_shufflevector(a, b, 0, 1, 2, 3, 4, 5, 6, 7);
}

// ---------------- Phase 0: W_ih -> bf16, K zero-padded to 320 --------------
__global__ __launch_bounds__(256) void wcvt_bf16(const float* __restrict__ W,
                                                 short* __restrict__ W16) {
  const int i = blockIdx.x * 256 + threadIdx.x;
  if (i >= HIDDEN * KPAD) return;
  const int n = i / KPAD, k = i % KPAD;
  W16[i] = (k < KIN) ? f2bf(W[n * KIN + k]) : (short)0;
}

// ---------------- Phase 1: xp = x @ W_ih^T + bias, DMA-native layout -------
// NEW vs r5: tile halved to 32 rows (16 batches x 2 timesteps) -> 512 blocks
// = 2 blocks/CU (8 waves/CU). Same total HBM traffic; per-block serial
// stage->sync->K-loop->sync->epilogue chain halves, and a co-resident block
// hides the other's latency. Emits the r2-scan xp16 contract:
// per (t,bg): [g=h/4][b][4] (g-stride 64, b-stride 4 shorts).
__global__ __launch_bounds__(256) void xp_gemm_mfma(
    const float* __restrict__ x, const short* __restrict__ W16,
    const float* __restrict__ b_ih, const float* __restrict__ b_hh,
    short* __restrict__ xp16) {
  __shared__ __align__(16) short As[32 * ASTR];  // 21.25 KB; epilogue stage too
  const int tid = threadIdx.x;
  const int lane = tid & 63, w = tid >> 6;
  const int q = lane >> 4, c = lane & 15;
  const int bg = blockIdx.x & 15, tc = blockIdx.x >> 4;  // tc 0..31
  const int b0 = bg * 16, t0 = tc * 2;

  // ---- stage x tile (32 rows x 300 K) as bf16, padded stride ASTR ----
#pragma unroll
  for (int i = 0; i < 10; ++i) {
    const int f = tid + 256 * i;  // float4 index over 32*75
    if (f < 2400) {
      const int rr = f / 75;
      const int k4 = f - rr * 75;
      const int b_in = rr >> 1, t_loc = rr & 1;
      const float4 v = *(const float4*)(
          x + ((size_t)(b0 + b_in) * TSZ + t0 + t_loc) * KIN + k4 * 4);
      uint2 pv;
      pv.x = pack2bf(v.x, v.y);
      pv.y = pack2bf(v.z, v.w);
      *(uint2*)&As[rr * ASTR + k4 * 4] = pv;
    }
  }
  if (tid < 32) {  // zero-pad k = 300..319
    const uint2 z = {0u, 0u};
#pragma unroll
    for (int j = 0; j < 5; ++j) *(uint2*)&As[tid * ASTR + 300 + j * 4] = z;
  }
  __syncthreads();

  // wave w owns h-tiles {2w, 2w+1} x 2 row-tiles
  f32x4 acc[2][2];
#pragma unroll
  for (int ht = 0; ht < 2; ++ht)
#pragma unroll
    for (int rt = 0; rt < 2; ++rt) acc[ht][rt] = (f32x4){0.f, 0.f, 0.f, 0.f};

  // A-frags (W16, L2-resident): lane (q,c) -> A[m=c][k=q*8+j]
  const short* wp0 = W16 + (size_t)((2 * w + 0) * 16 + c) * KPAD + q * 8;
  const short* wp1 = W16 + (size_t)((2 * w + 1) * 16 + c) * KPAD + q * 8;
  // B-frag LDS base for this lane
  const short* bqp = &As[c * ASTR + q * 8];
  short8 af[2][2];
  short8 bq[2][2];
  af[0][0] = *(const short8*)(wp0);
  af[0][1] = *(const short8*)(wp1);
#pragma unroll
  for (int rt = 0; rt < 2; ++rt)
    bq[0][rt] = *(const short8*)(bqp + rt * 16 * ASTR);
#pragma unroll
  for (int kc = 0; kc < 10; ++kc) {
    const int cur = kc & 1;
    if (kc < 9) {
      af[cur ^ 1][0] = *(const short8*)(wp0 + (kc + 1) * 32);
      af[cur ^ 1][1] = *(const short8*)(wp1 + (kc + 1) * 32);
#pragma unroll
      for (int rt = 0; rt < 2; ++rt)
        bq[cur ^ 1][rt] = *(const short8*)(bqp + rt * 16 * ASTR + (kc + 1) * 32);
    }
#pragma unroll
    for (int ht = 0; ht < 2; ++ht)
#pragma unroll
      for (int rt = 0; rt < 2; ++rt)
        acc[ht][rt] = __builtin_amdgcn_mfma_f32_16x16x32_bf16(
            af[cur][ht], bq[cur][rt], acc[ht][rt], 0, 0, 0);
  }
  __syncthreads();  // all B-frag reads done; As becomes the stage buffer

  // ---- epilogue: bias, pack, LDS transpose to [t][g][b][4] (padded) ----
  float4 bsum[2];
#pragma unroll
  for (int ht = 0; ht < 2; ++ht) {
    const int h0 = (2 * w + ht) * 16 + q * 4;
    const float4 bi = *(const float4*)(b_ih + h0);
    const float4 bh = *(const float4*)(b_hh + h0);
    bsum[ht] = make_float4(bi.x + bh.x, bi.y + bh.y, bi.z + bh.z, bi.w + bh.w);
  }
  // stage layout: t_loc stride 2312, g stride 72, b_in stride 4 (shorts)
#pragma unroll
  for (int ht = 0; ht < 2; ++ht) {
    const int g = (2 * w + ht) * 4 + q;  // h-group = h/4, g in [0,32)
#pragma unroll
    for (int rt = 0; rt < 2; ++rt) {
      const int r_glob = rt * 16 + c;    // row within 32-row tile
      const int b_in = r_glob >> 1, t_loc = r_glob & 1;
      uint2 pv;
      pv.x = pack2bf(acc[ht][rt][0] + bsum[ht].x, acc[ht][rt][1] + bsum[ht].y);
      pv.y = pack2bf(acc[ht][rt][2] + bsum[ht].z, acc[ht][rt][3] + bsum[ht].w);
      *(uint2*)&As[t_loc * 2312 + g * 72 + b_in * 4] = pv;
    }
  }
  __syncthreads();
  // ---- coalesced copy-out: per t_loc a dense 4 KB region ----
#pragma unroll
  for (int i = 0; i < 2; ++i) {
    const int4 vv =
        *(const int4*)&As[i * 2312 + (tid >> 3) * 72 + (tid & 7) * 8];
    *(int4*)(xp16 + ((size_t)(t0 + i) * 16 + bg) * 2048 + tid * 8) = vv;
  }
}

// ---------------- Phase 2: MFMA-batched scan + fused FC --------------------
// EXACT r2/r3 scan (best measured: 190.4 us, 0 conflicts). 16 blocks x 512
// threads (8 waves), wave w owns h-out rows [16w,16w+16). ht rows stride 132
// shorts with the 8-value k-fragment SPLIT into two 4-short groups (cols g*4
// and 64+g*4): conflict-free h broadcast. xp preloaded per chunk.
__global__ __launch_bounds__(512, 2) void rnn_scan_dma(
    const short* __restrict__ xp16, const float* __restrict__ Whh,
    const float* __restrict__ fc_w, const float* __restrict__ fc_b,
    float* __restrict__ out) {
  __shared__ __align__(16) short xs[2][8][2048];  // 64 KB
  __shared__ __align__(16) short ht[2][16][132];  // 8.25 KB, split-col layout
  const int tid = threadIdx.x;
  const int lane = tid & 63, w = tid >> 6;      // w = 0..7
  const int q = lane >> 4, c = lane & 15;
  const int bg = blockIdx.x;

  // W_hh A-frags: wave w owns h-out rows [16w, 16w+16); one frag per K-chunk.
  short8 aw[4];
#pragma unroll
  for (int kc = 0; kc < 4; ++kc) {
    const float* src = Whh + (size_t)(w * 16 + c) * HIDDEN + kc * 32 + q * 8;
    const float4 v0 = *(const float4*)(src);
    const float4 v1 = *(const float4*)(src + 4);
    short8 t;
    t[0] = f2bf(v0.x); t[1] = f2bf(v0.y); t[2] = f2bf(v0.z); t[3] = f2bf(v0.w);
    t[4] = f2bf(v1.x); t[5] = f2bf(v1.y); t[6] = f2bf(v1.z); t[7] = f2bf(v1.w);
    aw[kc] = t;
  }

  // h0 = 0
  {
    uint32_t* z = (uint32_t*)&ht[0][0][0];
    for (int i = tid; i < 2112; i += 512) z[i] = 0;
  }

  // DMA issue: wave w covers chunk-step s = w, 4 x 1KB insts
#define ISSUE_CHUNK(CH, BUF)                                                  \
  {                                                                           \
    const short* srcb =                                                       \
        xp16 + ((size_t)((CH)*8 + w) * 16 + bg) * 2048 + lane * 8;            \
    _Pragma("unroll") for (int j = 0; j < 4; ++j)                             \
        dma16(srcb + j * 512, &xs[BUF][w][j * 512]);                          \
  }

  ISSUE_CHUNK(0, 0)
  barrier_all();  // chunk-0 DMA landed; ht zero + everyone ready

  const int gx = (w * 4 + q) * 64 + c * 4;  // xs offset: h-group w*4+q, batch c
  // split-layout write base: rows k = w*16+q*4+{0..3} -> 8-group 2w+(q>>1),
  // j = (q&1)*4+r -> col = (q&1)*64 + (2w+(q>>1))*4 + r
  const int cb = (q & 1) * 64 + (2 * w + (q >> 1)) * 4;
  // split-layout read base for chunk kc: cols 16*kc+4*q (+64 for j>=4)
  const short* bhp0 = &ht[0][c][4 * q];
  const short* bhp1 = &ht[1][c][4 * q];

  for (int cc = 0; cc < 64; ++cc) {
    const int buf = cc & 1;
    if (cc + 1 < 64) ISSUE_CHUNK(cc + 1, buf ^ 1)
    // preload the whole chunk's xp for this lane (h-independent, dbuf'd)
    uint2 us[8];
#pragma unroll
    for (int s = 0; s < 8; ++s) us[s] = *(const uint2*)&xs[buf][s][gx];
#pragma unroll
    for (int s = 0; s < 8; ++s) {
      const int rb = s & 1;  // global t = cc*8+s; cc even so parity = s&1
      const short* bp = rb ? bhp1 : bhp0;
      const short8 bh0 = ld_bh(bp + 0);
      const short8 bh1 = ld_bh(bp + 16);
      const short8 bh2 = ld_bh(bp + 32);
      const short8 bh3 = ld_bh(bp + 48);
      f32x4 a0 = {bflo(us[s].x), bfhi(us[s].x), bflo(us[s].y), bfhi(us[s].y)};
      f32x4 a2 = {0.f, 0.f, 0.f, 0.f};
      a0 = __builtin_amdgcn_mfma_f32_16x16x32_bf16(aw[0], bh0, a0, 0, 0, 0);
      a2 = __builtin_amdgcn_mfma_f32_16x16x32_bf16(aw[2], bh2, a2, 0, 0, 0);
      a0 = __builtin_amdgcn_mfma_f32_16x16x32_bf16(aw[1], bh1, a0, 0, 0, 0);
      a2 = __builtin_amdgcn_mfma_f32_16x16x32_bf16(aw[3], bh3, a2, 0, 0, 0);
      const f32x4 s0 = a0 + a2;
      uint2 w0;
      w0.x = pack2bf(tanhf_fast(s0[0]), tanhf_fast(s0[1]));
      w0.y = pack2bf(tanhf_fast(s0[2]), tanhf_fast(s0[3]));
      *(uint2*)&ht[rb ^ 1][c][cb] = w0;
      barrier_lds();
    }
    barrier_all();  // next chunk's DMA (issued ~8 steps ago) must be landed
  }
#undef ISSUE_CHUNK

  // h_last in ht[0] (t=511 wrote rb^1 = 0). FC: 32 outputs/block.
  // Split layout: k = g8*8 + j; j<4 at col g8*4+j, j>=4 at col 64+g8*4+(j-4).
  if (tid < 32) {
    const int bi = tid >> 1, cls = tid & 1;
    float s = fc_b[cls];
    const float* fw = fc_w + cls * HIDDEN;
#pragma unroll 4
    for (int g8 = 0; g8 < 16; ++g8) {
#pragma unroll
      for (int j = 0; j < 4; ++j) {
        s = fmaf(bf2f(ht[0][bi][g8 * 4 + j]), fw[g8 * 8 + j], s);
        s = fmaf(bf2f(ht[0][bi][64 + g8 * 4 + j]), fw[g8 * 8 + 4 + j], s);
      }
    }
    out[(bg * 16 + bi) * 2 + cls] = s;
  }
}

extern "C" void kernel_launch(void* const* d_in, const int* in_sizes, int n_in,
                              void* d_out, int out_size, void* d_ws, size_t ws_size,
                              hipStream_t stream) {
  const float* x    = (const float*)d_in[0];
  const float* W_ih = (const float*)d_in[1];
  const float* W_hh = (const float*)d_in[2];
  const float* b_ih = (const float*)d_in[3];
  const float* b_hh = (const float*)d_in[4];
  const float* fc_w = (const float*)d_in[5];
  const float* fc_b = (const float*)d_in[6];
  short* xp16 = (short*)d_ws;                         // 32 MiB bf16 [T][16bg][2048]
  short* W16  = (short*)((char*)d_ws + (33u << 20));  // 80 KB bf16 [128][320]
  float* out  = (float*)d_out;

  wcvt_bf16<<<(HIDDEN * KPAD + 255) / 256, 256, 0, stream>>>(W_ih, W16);
  xp_gemm_mfma<<<16 * (TSZ / 2), 256, 0, stream>>>(x, W16, b_ih, b_hh, xp16);
  rnn_scan_dma<<<16, 512, 0, stream>>>(xp16, W_hh, fc_w, fc_b, out);
}